// Round 10
// baseline (1436.630 us; speedup 1.0000x reference)
//
#include <hip/hip_runtime.h>
#include <hip/hip_bf16.h>
#include <cstdint>

typedef unsigned int u32;
typedef unsigned short u16;
typedef __attribute__((ext_vector_type(8))) short bf16x8;
typedef __attribute__((ext_vector_type(4))) float f32x4;

#define TT 128
#define BB 512
#define DD 128
#define HH 256
#define CC 512

// recurrent LDS map (u32 units): hl[0,32768) hd0 hd1 P0 P1 (2048 each) = 160KB exact
#define HD0O 32768
#define HD1O 34816
#define P0O  36864
#define P1O  38912

// raw barrier: LDS ordering only — do NOT drain vmcnt (stores/prefetch stay in flight)
#define BAR() do { asm volatile("s_waitcnt lgkmcnt(0)" ::: "memory"); \
                   __builtin_amdgcn_s_barrier(); \
                   asm volatile("" ::: "memory"); } while(0)

__device__ __forceinline__ u16 f2bf(float f){
  u32 u = __builtin_bit_cast(u32, f);
  u += 0x7FFFu + ((u >> 16) & 1u);
  return (u16)(u >> 16);
}
__device__ __forceinline__ float bflo(u32 w){ return __builtin_bit_cast(float, w << 16); }
__device__ __forceinline__ float bfhi(u32 w){ return __builtin_bit_cast(float, w & 0xFFFF0000u); }
__device__ __forceinline__ float bf1(u16 w){ return __builtin_bit_cast(float, ((u32)w) << 16); }
__device__ __forceinline__ float sigm(float x){ return 1.f / (1.f + __expf(-x)); }
__device__ __forceinline__ float tanh_fast(float x){
  float t = __expf(-2.f * fabsf(x));
  float r = (1.f - t) / (1.f + t);
  return copysignf(r, x);
}

// Kernel 0: pack weights (unchanged).
__global__ __launch_bounds__(256) void prep_weights(
    const float* __restrict__ zl_w, const float* __restrict__ rl_w,
    const float* __restrict__ hl_w, const float* __restrict__ gh_w,
    const float* __restrict__ gx_w,
    u32* __restrict__ zlB, u32* __restrict__ rlB, u32* __restrict__ hlF,
    u32* __restrict__ Bpre, u32* __restrict__ ghF, float* __restrict__ gxd){
  int gid = blockIdx.x * 256 + threadIdx.x;   // 0..65535
  if (gid < 32768){
    int d   = gid & 3;
    int l   = (gid >> 2) & 63;
    int kt  = (gid >> 8) & 7;
    int ntg = (gid >> 11) & 15;
    int nn  = 16*ntg + (l & 15);
    int kk  = 32*kt + 8*(l >> 4) + 2*d;
    int c0 = 128 + kk;
    zlB[gid] = (u32)f2bf(zl_w[nn*CC + c0]) | ((u32)f2bf(zl_w[nn*CC + c0 + 1]) << 16);
    rlB[gid] = (u32)f2bf(rl_w[nn*CC + c0]) | ((u32)f2bf(rl_w[nn*CC + c0 + 1]) << 16);
    hlF[gid] = (u32)f2bf(hl_w[nn*CC + c0]) | ((u32)f2bf(hl_w[nn*CC + c0 + 1]) << 16);
  }
  #pragma unroll
  for (int q = 0; q < 2; ++q){
    int id = q*65536 + gid;
    if (id < 98304){
      int d2 = id & 3;
      int l  = (id >> 2) & 63;
      int kt = (id >> 8) & 7;
      int nt = id >> 11;            // 0..47
      int g  = nt >> 4;
      int nc = (nt & 15)*16 + (l & 15);
      int k  = 32*kt + 8*(l >> 4) + 2*d2;
      int sc = (k < 128) ? k : k + 256;
      const float* W = (g == 0) ? zl_w : ((g == 1) ? rl_w : hl_w);
      Bpre[id] = (u32)f2bf(W[nc*CC + sc]) | ((u32)f2bf(W[nc*CC + sc + 1]) << 16);
    }
  }
  if (gid < 16384){
    int d2 = gid & 3;
    int l  = (gid >> 2) & 63;
    int kt = (gid >> 8) & 3;
    int nt = gid >> 10;             // 0..15
    int nc = nt*16 + (l & 15);
    int k  = 32*kt + 8*(l >> 4) + 2*d2;
    ghF[gid] = (u32)f2bf(gh_w[nc*DD + k]) | ((u32)f2bf(gh_w[nc*DD + k + 1]) << 16);
  }
  if (gid < 128) gxd[gid] = gx_w[gid*DD + gid];
}

// Kernel 1: MFMA precompute. Outputs: zrp (bf16 z|r pair) and hpd (bf16 hpre|dh pair).
// Phase2 uses the same nt=4i+wn remap as phase1 so hpre/dh pack in-register.
__global__ __launch_bounds__(512, 2) void precompute_mfma(
    const float* __restrict__ input, const float* __restrict__ xmean,
    const float* __restrict__ gxd, const float* __restrict__ gx_b,
    const float* __restrict__ zl_b, const float* __restrict__ rl_b,
    const float* __restrict__ hl_b, const float* __restrict__ gh_b,
    const u32* __restrict__ Bpre, const u32* __restrict__ ghF,
    u32* __restrict__ zrp, u32* __restrict__ hpd){
  __shared__ __align__(16) u16 A1[4][8][64][8];   // 32 KB
  __shared__ __align__(16) u16 A2[4][4][64][8];   // 16 KB
  const int tid = threadIdx.x;
  const int r0 = blockIdx.x * 64;
  const int t  = r0 >> 9;
  const int b0 = r0 & 511;
  {
    int row = tid >> 3, dsg = tid & 7, d0 = dsg * 16;
    int b = b0 + row;
    const size_t ib = ((size_t)b * 4 * TT + t) * DD;
    int mt = row >> 4;
    #pragma unroll
    for (int gg = 0; gg < 2; ++gg){
      int db = d0 + 8*gg;
      float xv[8], lv[8], mv[8], dv[8], xm[8], gd[8], gb[8];
      #pragma unroll
      for (int q = 0; q < 2; ++q){
        *(float4*)&xv[q*4] = *(const float4*)&input[ib + 0*TT*DD + db + q*4];
        *(float4*)&lv[q*4] = *(const float4*)&input[ib + 1*TT*DD + db + q*4];
        *(float4*)&mv[q*4] = *(const float4*)&input[ib + 2*TT*DD + db + q*4];
        *(float4*)&dv[q*4] = *(const float4*)&input[ib + 3*TT*DD + db + q*4];
        *(float4*)&xm[q*4] = *(const float4*)&xmean[t*DD + db + q*4];
        *(float4*)&gd[q*4] = *(const float4*)&gxd[db + q*4];
        *(float4*)&gb[q*4] = *(const float4*)&gx_b[db + q*4];
      }
      union { u16 s[8]; bf16x8 v; } pe, pm, pd;
      #pragma unroll
      for (int j = 0; j < 8; ++j){
        float dxv = __expf(-fmaxf(dv[j]*gd[j] + gb[j], 0.f));
        float xe  = mv[j]*xv[j] + (1.f - mv[j])*(dxv*lv[j] + (1.f - dxv)*xm[j]);
        pe.s[j] = f2bf(xe);
        pm.s[j] = f2bf(mv[j]);
        pd.s[j] = f2bf(dv[j]);
      }
      int kt1 = db >> 5;
      int l1  = (row & 15) + 16*((db >> 3) & 3);
      *(bf16x8*)&A1[mt][kt1][l1][0]     = pe.v;
      *(bf16x8*)&A1[mt][4 + kt1][l1][0] = pm.v;
      *(bf16x8*)&A2[mt][kt1][l1][0]     = pd.v;
    }
  }
  __syncthreads();
  const int l = tid & 63, w = tid >> 6;
  const int wm = w >> 2, wn = w & 3;
  const int rowl = 4 * (l >> 4), coll = l & 15;
  // ---- phase 1: K=256, nt = 4i + wn
  f32x4 acc[2][12];
  #pragma unroll
  for (int m = 0; m < 2; ++m)
    #pragma unroll
    for (int i = 0; i < 12; ++i) acc[m][i] = (f32x4){0.f,0.f,0.f,0.f};
  #pragma unroll
  for (int kt = 0; kt < 8; ++kt){
    bf16x8 a0 = *(const bf16x8*)&A1[wm*2 + 0][kt][l][0];
    bf16x8 a1 = *(const bf16x8*)&A1[wm*2 + 1][kt][l][0];
    #pragma unroll
    for (int i = 0; i < 12; ++i){
      int nt = 4*i + wn;
      bf16x8 bf = *(const bf16x8*)(Bpre + ((nt*8 + kt)*64 + l)*4);
      acc[0][i] = __builtin_amdgcn_mfma_f32_16x16x32_bf16(a0, bf, acc[0][i], 0, 0, 0);
      acc[1][i] = __builtin_amdgcn_mfma_f32_16x16x32_bf16(a1, bf, acc[1][i], 0, 0, 0);
    }
  }
  // ---- phase 2: K=128, nt = 4i + wn (aligned with phase1 h-part)
  f32x4 ac2[2][4];
  #pragma unroll
  for (int m = 0; m < 2; ++m)
    #pragma unroll
    for (int i = 0; i < 4; ++i) ac2[m][i] = (f32x4){0.f,0.f,0.f,0.f};
  #pragma unroll
  for (int kt = 0; kt < 4; ++kt){
    bf16x8 a0 = *(const bf16x8*)&A2[wm*2 + 0][kt][l][0];
    bf16x8 a1 = *(const bf16x8*)&A2[wm*2 + 1][kt][l][0];
    #pragma unroll
    for (int i = 0; i < 4; ++i){
      int nt = 4*i + wn;
      bf16x8 bf = *(const bf16x8*)(ghF + ((nt*4 + kt)*64 + l)*4);
      ac2[0][i] = __builtin_amdgcn_mfma_f32_16x16x32_bf16(a0, bf, ac2[0][i], 0, 0, 0);
      ac2[1][i] = __builtin_amdgcn_mfma_f32_16x16x32_bf16(a1, bf, ac2[1][i], 0, 0, 0);
    }
  }
  // ---- stores
  #pragma unroll
  for (int m = 0; m < 2; ++m){
    int grow = r0 + wm*32 + m*16 + rowl;
    #pragma unroll
    for (int i = 0; i < 4; ++i){
      int lc = (4*i + wn)*16 + coll;
      float bz = zl_b[lc], br = rl_b[lc], bh = hl_b[lc], bg = gh_b[lc];
      #pragma unroll
      for (int rg = 0; rg < 4; ++rg){
        size_t o = (size_t)(grow + rg)*HH + lc;
        zrp[o] = (u32)f2bf(acc[m][i][rg] + bz) | ((u32)f2bf(acc[m][i+4][rg] + br) << 16);
        float dhv = __expf(-fmaxf(ac2[m][i][rg] + bg, 0.f));
        hpd[o] = (u32)f2bf(acc[m][i+8][rg] + bh) | ((u32)f2bf(dhv) << 16);
      }
    }
  }
}

// Kernel 2: MFMA recurrence, 2 independent 8-row streams per block (ILP-2 on every
// stall class; barriers amortized over both). Rows 8-15 of each 16-row tile are
// benign garbage (row-local in MFMA, never stored; loads clamp &7 onto real rows).
__global__ __launch_bounds__(512, 2) void recurrent_mfma(
    const u32* __restrict__ zrp, const u32* __restrict__ hpd,
    const u32* __restrict__ zlB, const u32* __restrict__ rlB,
    const u32* __restrict__ hlF, u16* __restrict__ hout){
  __shared__ u32 smem[40960];   // 160 KB exact
  const int tid = threadIdx.x;
  const int l = tid & 63, w = tid >> 6;
  const int b0 = blockIdx.x * 16;
  const int rowb = 4 * (l >> 4);          // 0,4,8,12 ; valid rows: rowb<8 (lanes 0-31)
  const int col0 = 32*w + (l & 15);
  const int rcl  = (rowb) & 7;            // clamped row base for loads
  const bool valid = (rowb < 8);

  #pragma unroll
  for (int i = 0; i < 64; ++i) smem[i*512 + tid] = hlF[i*512 + tid];
  #pragma unroll
  for (int i = 0; i < 8; ++i) smem[HD0O + i*512 + tid] = 0;   // zero hd0,hd1,P0,P1

  bf16x8 zb[2][8], rb[2][8];
  #pragma unroll
  for (int nt = 0; nt < 2; ++nt){
    #pragma unroll
    for (int kt = 0; kt < 8; ++kt){
      int off = (((w*2 + nt)*8 + kt)*64 + l)*4;
      zb[nt][kt] = *(const bf16x8*)(zlB + off);
      rb[nt][kt] = *(const bf16x8*)(rlB + off);
    }
  }
  __syncthreads();

  int scb[2];
  #pragma unroll
  for (int nt = 0; nt < 2; ++nt)
    scb[nt] = w*512 + (2*nt + ((l >> 3) & 1))*128 + rowb*8 + (l & 7);

  float hdreg[2][2][4];   // [g][nt][jr]
  #pragma unroll
  for (int g = 0; g < 2; ++g)
    #pragma unroll
    for (int nt = 0; nt < 2; ++nt)
      #pragma unroll
      for (int jr = 0; jr < 4; ++jr) hdreg[g][nt][jr] = 0.f;

  u16* pa16[2] = { (u16*)(smem + P0O),  (u16*)(smem + P1O)  };
  u16* hd16[2] = { (u16*)(smem + HD0O), (u16*)(smem + HD1O) };

  // pipeline registers
  u32 zrC[2][2][4], hpC[2][2][4];
  #pragma unroll
  for (int g = 0; g < 2; ++g)
    #pragma unroll
    for (int nt = 0; nt < 2; ++nt)
      #pragma unroll
      for (int jr = 0; jr < 4; ++jr){
        size_t o = ((size_t)b0 + 8*g + rcl + jr)*HH + col0 + 16*nt;   // t=0
        zrC[g][nt][jr] = zrp[o];
        hpC[g][nt][jr] = hpd[o];
      }

  for (int t = 0; t < TT; ++t){
    // ---- prefetch t+1, both streams
    u32 zrN[2][2][4], hpN[2][2][4];
    {
      int tn = (t < TT-1) ? t+1 : TT-1;
      #pragma unroll
      for (int g = 0; g < 2; ++g)
        #pragma unroll
        for (int nt = 0; nt < 2; ++nt)
          #pragma unroll
          for (int jr = 0; jr < 4; ++jr){
            size_t o = ((size_t)tn*BB + b0 + 8*g + rcl + jr)*HH + col0 + 16*nt;
            zrN[g][nt][jr] = zrp[o];
            hpN[g][nt][jr] = hpd[o];
          }
    }
    // ---- zr GEMMs, both streams (8 independent accumulate chains)
    f32x4 cz[2][2], cr[2][2];
    #pragma unroll
    for (int g = 0; g < 2; ++g)
      #pragma unroll
      for (int nt = 0; nt < 2; ++nt){ cz[g][nt] = (f32x4){0,0,0,0}; cr[g][nt] = (f32x4){0,0,0,0}; }
    #pragma unroll
    for (int kt = 0; kt < 8; ++kt){
      bf16x8 a0 = *(const bf16x8*)(smem + HD0O + kt*256 + l*4);
      bf16x8 a1 = *(const bf16x8*)(smem + HD1O + kt*256 + l*4);
      cz[0][0] = __builtin_amdgcn_mfma_f32_16x16x32_bf16(a0, zb[0][kt], cz[0][0], 0, 0, 0);
      cz[1][0] = __builtin_amdgcn_mfma_f32_16x16x32_bf16(a1, zb[0][kt], cz[1][0], 0, 0, 0);
      cz[0][1] = __builtin_amdgcn_mfma_f32_16x16x32_bf16(a0, zb[1][kt], cz[0][1], 0, 0, 0);
      cz[1][1] = __builtin_amdgcn_mfma_f32_16x16x32_bf16(a1, zb[1][kt], cz[1][1], 0, 0, 0);
      cr[0][0] = __builtin_amdgcn_mfma_f32_16x16x32_bf16(a0, rb[0][kt], cr[0][0], 0, 0, 0);
      cr[1][0] = __builtin_amdgcn_mfma_f32_16x16x32_bf16(a1, rb[0][kt], cr[1][0], 0, 0, 0);
      cr[0][1] = __builtin_amdgcn_mfma_f32_16x16x32_bf16(a0, rb[1][kt], cr[0][1], 0, 0, 0);
      cr[1][1] = __builtin_amdgcn_mfma_f32_16x16x32_bf16(a1, rb[1][kt], cr[1][1], 0, 0, 0);
    }
    // ---- gates both streams; write P tiles
    float zreg[2][2][4];
    #pragma unroll
    for (int g = 0; g < 2; ++g)
      #pragma unroll
      for (int nt = 0; nt < 2; ++nt)
        #pragma unroll
        for (int jr = 0; jr < 4; ++jr){
          float zv = sigm(bflo(zrC[g][nt][jr]) + cz[g][nt][jr]);
          float rv = sigm(bfhi(zrC[g][nt][jr]) + cr[g][nt][jr]);
          zreg[g][nt][jr] = zv;
          pa16[g][scb[nt] + jr*8] = f2bf(rv * hdreg[g][nt][jr]);
        }
    BAR();   // S1: P0,P1 visible
    // ---- htilde GEMMs, both streams
    f32x4 ch[2][2];
    #pragma unroll
    for (int g = 0; g < 2; ++g)
      #pragma unroll
      for (int nt = 0; nt < 2; ++nt) ch[g][nt] = (f32x4){0,0,0,0};
    #pragma unroll
    for (int kt = 0; kt < 8; ++kt){
      bf16x8 p0 = *(const bf16x8*)(smem + P0O + kt*256 + l*4);
      bf16x8 p1 = *(const bf16x8*)(smem + P1O + kt*256 + l*4);
      bf16x8 bh0 = *(const bf16x8*)(smem + ((2*w+0)*8 + kt)*256 + l*4);
      bf16x8 bh1 = *(const bf16x8*)(smem + ((2*w+1)*8 + kt)*256 + l*4);
      ch[0][0] = __builtin_amdgcn_mfma_f32_16x16x32_bf16(p0, bh0, ch[0][0], 0, 0, 0);
      ch[1][0] = __builtin_amdgcn_mfma_f32_16x16x32_bf16(p1, bh0, ch[1][0], 0, 0, 0);
      ch[0][1] = __builtin_amdgcn_mfma_f32_16x16x32_bf16(p0, bh1, ch[0][1], 0, 0, 0);
      ch[1][1] = __builtin_amdgcn_mfma_f32_16x16x32_bf16(p1, bh1, ch[1][1], 0, 0, 0);
    }
    // ---- combine both streams; emit h (valid lanes only), stage hd(t+1)
    #pragma unroll
    for (int g = 0; g < 2; ++g)
      #pragma unroll
      for (int nt = 0; nt < 2; ++nt)
        #pragma unroll
        for (int jr = 0; jr < 4; ++jr){
          float ht = tanh_fast(bflo(hpC[g][nt][jr]) + ch[g][nt][jr]);
          float hd = hdreg[g][nt][jr];
          float zv = zreg[g][nt][jr];
          float hn = (1.f - zv)*hd + zv*ht;
          if (valid){
            size_t o = ((size_t)t*BB + b0 + 8*g + rowb + jr)*HH + col0 + 16*nt;
            hout[o] = f2bf(hn);
          }
          float hdn = bfhi(hpN[g][nt][jr]) * hn;   // dh[t+1] from prefetched pack
          hdreg[g][nt][jr] = hdn;
          hd16[g][scb[nt] + jr*8] = f2bf(hdn);
        }
    BAR();   // S2: hd(t+1) visible
    // ---- rotate
    #pragma unroll
    for (int g = 0; g < 2; ++g)
      #pragma unroll
      for (int nt = 0; nt < 2; ++nt)
        #pragma unroll
        for (int jr = 0; jr < 4; ++jr){
          zrC[g][nt][jr] = zrN[g][nt][jr];
          hpC[g][nt][jr] = hpN[g][nt][jr];
        }
  }
}

// Kernel 3: out[b,t] = sigmoid(h[t,b,:] . fc_w + fc_b). One wave per row.
__global__ __launch_bounds__(256) void head(const u16* __restrict__ hout,
    const float* __restrict__ fc_w, const float* __restrict__ fc_b,
    float* __restrict__ out){
  int w = threadIdx.x >> 6, lane = threadIdx.x & 63;
  int rr = blockIdx.x * 4 + w;           // rr = t*BB + b
  const ushort4 hv = *(const ushort4*)&hout[(size_t)rr*HH + lane*4];
  const float4 fw = *(const float4*)&fc_w[lane*4];
  float s = bf1(hv.x)*fw.x + bf1(hv.y)*fw.y + bf1(hv.z)*fw.z + bf1(hv.w)*fw.w;
  #pragma unroll
  for (int o = 32; o >= 1; o >>= 1) s += __shfl_xor(s, o, 64);
  if (lane == 0){
    int t = rr >> 9, b = rr & 511;
    out[b*TT + t] = sigm(s + fc_b[0]);
  }
}

extern "C" void kernel_launch(void* const* d_in, const int* in_sizes, int n_in,
                              void* d_out, int out_size, void* d_ws, size_t ws_size,
                              hipStream_t stream) {
  const float* input = (const float*)d_in[0];
  const float* xmean = (const float*)d_in[1];
  const float* zl_w  = (const float*)d_in[2];
  const float* zl_b  = (const float*)d_in[3];
  const float* rl_w  = (const float*)d_in[4];
  const float* rl_b  = (const float*)d_in[5];
  const float* hl_w  = (const float*)d_in[6];
  const float* hl_b  = (const float*)d_in[7];
  const float* gx_w  = (const float*)d_in[8];
  const float* gx_b  = (const float*)d_in[9];
  const float* gh_w  = (const float*)d_in[10];
  const float* gh_b  = (const float*)d_in[11];
  const float* fc_w  = (const float*)d_in[12];
  const float* fc_b  = (const float*)d_in[13];
  float* out = (float*)d_out;

  const size_t S = (size_t)TT * BB * HH;   // 16,777,216
  u32*   zrp  = (u32*)d_ws;                // S u32 (z|r bf16 pair)
  u32*   hpd  = zrp + S;                   // S u32 (hpre|dh bf16 pair)
  u16*   hout = (u16*)(hpd + S);           // S u16
  u32*   zlB  = (u32*)(hout + S);
  u32*   rlB  = zlB + 32768;
  u32*   hlF  = rlB + 32768;
  u32*   Bpre = hlF + 32768;
  u32*   ghF  = Bpre + 98304;
  float* gxd  = (float*)(ghF + 16384);

  prep_weights<<<256, 256, 0, stream>>>(zl_w, rl_w, hl_w, gh_w, gx_w,
                                        zlB, rlB, hlF, Bpre, ghF, gxd);
  precompute_mfma<<<1024, 512, 0, stream>>>(input, xmean, gxd, gx_b,
                                            zl_b, rl_b, hl_b, gh_b,
                                            Bpre, ghF, zrp, hpd);
  recurrent_mfma<<<32, 512, 0, stream>>>(zrp, hpd, zlB, rlB, hlF, hout);
  head<<<16384, 256, 0, stream>>>(hout, fc_w, fc_b, out);
}